// Round 1
// baseline (145.050 us; speedup 1.0000x reference)
//
#include <hip/hip_runtime.h>
#include <hip/hip_bf16.h>
#include <stdint.h>

#define Bdim 64
#define Ldim 16
#define Fdim 64
#define Rdim 1023
#define RP   1024
#define Mdim (Bdim*Fdim)          // 4096
#define BFR  (Bdim*Fdim*Rdim)     // 4190208

typedef __bf16 bf16;
typedef __bf16 bf16x8 __attribute__((ext_vector_type(8)));
typedef float  f32x4  __attribute__((ext_vector_type(4)));

// ---------------------------------------------------------------------------
// async global->LDS 16B copy (wave-uniform LDS base + lane*16)
// ---------------------------------------------------------------------------
__device__ __forceinline__ void async16(const void* g, void* l) {
    __builtin_amdgcn_global_load_lds(
        (const __attribute__((address_space(1))) void*)g,
        (__attribute__((address_space(3))) void*)l,
        16, 0, 0);
}

// ---------------------------------------------------------------------------
// Kernel A: fused 4-way weighted reduction over l, fp32 -> bf16 (padded K)
// args layout (bf16):
//   [0)          car_arg  (4096 x 1024)
//   [4194304)    cdr_arg  (4096 x 1024)
//   [8388608)    cons12   (4096 x 2048)  cols 0..1023 = c1, 1024..2047 = c2
// ---------------------------------------------------------------------------
__global__ __launch_bounds__(256) void k_args(
    const float* __restrict__ x,
    const float* __restrict__ w0, const float* __restrict__ w1,
    const float* __restrict__ w2, const float* __restrict__ w3,
    bf16* __restrict__ args)
{
    int blk = blockIdx.x;             // m = b*64 + f
    int b = blk >> 6, f = blk & 63;
    int t = threadIdx.x;

    // wave-uniform weight loads -> compiler scalarizes into SGPRs
    float wr0[16], wr1[16], wr2[16], wr3[16];
#pragma unroll
    for (int l = 0; l < 16; ++l) {
        wr0[l] = w0[b*16 + l];
        wr1[l] = w1[b*16 + l];
        wr2[l] = w2[b*16 + l];
        wr3[l] = w3[b*16 + l];
    }

    const float* xb = x + ((size_t)(b*16)*64 + f) * (size_t)Rdim;  // x[b][0][f][0]
    bf16* car = args + (size_t)blk * RP;
    bf16* cdr = args + 4194304 + (size_t)blk * RP;
    bf16* c12 = args + 8388608 + (size_t)blk * 2048;

#pragma unroll
    for (int it = 0; it < 4; ++it) {
        int r = t + it * 256;          // 0..1023, r==1023 only for t=255,it=3
        float a0 = 0.f, a1 = 0.f, a2 = 0.f, a3 = 0.f;
        if (r < Rdim) {
#pragma unroll
            for (int l = 0; l < 16; ++l) {
                float v = xb[(size_t)l * (64 * (size_t)Rdim) + r];
                a0 += wr0[l] * v;
                a1 += wr1[l] * v;
                a2 += wr2[l] * v;
                a3 += wr3[l] * v;
            }
        }
        car[r]        = (bf16)a0;
        cdr[r]        = (bf16)a1;
        c12[r]        = (bf16)a2;
        c12[1024 + r] = (bf16)a3;
    }
}

// ---------------------------------------------------------------------------
// Kernel B: convert+pad role matrices to bf16, K-major (N-row, K-contig)
// dpad layout (bf16):
//   [0)        D_l  (1024 x 1024)
//   [1048576)  D_r  (1024 x 1024)
//   [2097152)  E    (1024 x 2048)  cols 0..1023 = E_l row, 1024.. = E_r row
// ---------------------------------------------------------------------------
__global__ __launch_bounds__(256) void k_convd(
    const float* __restrict__ Dl, const float* __restrict__ Dr,
    const float* __restrict__ El, const float* __restrict__ Er,
    bf16* __restrict__ dpad)
{
    int id = blockIdx.x * 256 + threadIdx.x;      // 0 .. 4M-1
    int mat = id >> 20;
    int rem = id & 1048575;
    int n = rem >> 10, k = rem & 1023;
    const float* src = (mat == 0) ? Dl : (mat == 1) ? Dr : (mat == 2) ? El : Er;
    float v = (n < Rdim && k < Rdim) ? src[n * Rdim + k] : 0.f;
    size_t dst;
    if (mat == 0)      dst = (size_t)n * 1024 + k;
    else if (mat == 1) dst = 1048576 + (size_t)n * 1024 + k;
    else if (mat == 2) dst = 2097152 + (size_t)n * 2048 + k;
    else               dst = 2097152 + (size_t)n * 2048 + 1024 + k;
    dpad[dst] = (bf16)v;
}

// ---------------------------------------------------------------------------
// Kernel C: bf16 MFMA GEMM.  C[m,n] = sum_k A[m,k]*Bm[n,k]
// 128x128 tile, 4 waves (2x2), each wave 64x64 = 4x4 frags of 16x16x32.
// grid = (32, 8, 3); z = job {car, cdr, cons}
// ---------------------------------------------------------------------------
__global__ __launch_bounds__(256) void k_gemm(
    const bf16* __restrict__ args, const bf16* __restrict__ dpad,
    const float* __restrict__ root_filler, const float* __restrict__ root_role,
    float* __restrict__ out)
{
    const int job = blockIdx.z;
    const int tm  = blockIdx.x;      // 0..31
    const int tn  = blockIdx.y;      // 0..7
    const int K   = (job == 2) ? 2048 : 1024;

    const bf16* A  = args + ((job == 0) ? 0u : (job == 1) ? 4194304u : 8388608u);
    const bf16* Bm = dpad + ((job == 0) ? 0u : (job == 1) ? 1048576u : 2097152u);
    float* outp = out + (size_t)job * BFR;

    __shared__ bf16 As[128 * 32];
    __shared__ bf16 Bs[128 * 32];

    const int t    = threadIdx.x;
    const int wave = t >> 6, lane = t & 63;
    const int wr   = wave >> 1, wc = wave & 1;
    const int lr   = lane & 15, lk = lane >> 4;

    f32x4 acc[4][4] = {};

    // staging: linear [128][32]bf16 tile; thread t covers bytes [t*16, t*16+16)
    const int row0 = t >> 2;              // (t*16)/64
    const int cb0  = (t & 3) * 16;        // byte col within 64B row

    const char* Ab1 = (const char*)(A  + (size_t)(tm * 128 +      row0) * K) + cb0;
    const char* Ab2 = (const char*)(A  + (size_t)(tm * 128 + 64 + row0) * K) + cb0;
    const char* Bb1 = (const char*)(Bm + (size_t)(tn * 128 +      row0) * K) + cb0;
    const char* Bb2 = (const char*)(Bm + (size_t)(tn * 128 + 64 + row0) * K) + cb0;

    char* AsW1 = (char*)As        + wave * 1024;   // wave-uniform LDS bases
    char* AsW2 = (char*)As + 4096 + wave * 1024;
    char* BsW1 = (char*)Bs        + wave * 1024;
    char* BsW2 = (char*)Bs + 4096 + wave * 1024;

    for (int k0 = 0; k0 < K; k0 += 32) {
        size_t kb = (size_t)k0 * 2;
        async16(Ab1 + kb, AsW1);
        async16(Ab2 + kb, AsW2);
        async16(Bb1 + kb, BsW1);
        async16(Bb2 + kb, BsW2);
        __syncthreads();

        bf16x8 af[4], bf[4];
#pragma unroll
        for (int i = 0; i < 4; ++i)
            af[i] = *(const bf16x8*)(As + (wr * 64 + i * 16 + lr) * 32 + lk * 8);
#pragma unroll
        for (int j = 0; j < 4; ++j)
            bf[j] = *(const bf16x8*)(Bs + (wc * 64 + j * 16 + lr) * 32 + lk * 8);

#pragma unroll
        for (int i = 0; i < 4; ++i)
#pragma unroll
            for (int j = 0; j < 4; ++j)
                acc[i][j] = __builtin_amdgcn_mfma_f32_16x16x32_bf16(af[i], bf[j], acc[i][j], 0, 0, 0);

        __syncthreads();
    }

    // epilogue: C/D layout: col = lane&15, row = (lane>>4)*4 + q
#pragma unroll
    for (int i = 0; i < 4; ++i) {
        int gm = tm * 128 + wr * 64 + i * 16 + lk * 4;
#pragma unroll
        for (int j = 0; j < 4; ++j) {
            int gn = tn * 128 + wc * 64 + j * 16 + lr;
            if (gn < Rdim) {
                float rr = (job == 2) ? root_role[gn] : 0.f;
#pragma unroll
                for (int q = 0; q < 4; ++q) {
                    float v = acc[i][j][q];
                    if (job == 2) v += root_filler[gm + q] * rr;
                    outp[(size_t)(gm + q) * Rdim + gn] = v;
                }
            }
        }
    }
}

// ---------------------------------------------------------------------------
// Kernel D: entropies and maxes of the 4 weight vectors
// ---------------------------------------------------------------------------
__global__ __launch_bounds__(256) void k_stats(
    const float* __restrict__ w0, const float* __restrict__ w1,
    const float* __restrict__ w2, const float* __restrict__ w3,
    float* __restrict__ out)
{
    int t = threadIdx.x;
    int k = t >> 6, b = t & 63;
    const float* w = (k == 0) ? w0 : (k == 1) ? w1 : (k == 2) ? w2 : w3;
    float s = 0.f, mx = -1e30f;
#pragma unroll
    for (int l = 0; l < 16; ++l) {
        float p = w[b * 16 + l];
        s += p * logf(p + 1e-12f);
        mx = fmaxf(mx, p);
    }
    float ent = -s / logf(16.f);
    out[3 * (size_t)BFR + k * 64 + b]       = ent;
    out[3 * (size_t)BFR + 256 + k * 64 + b] = mx;
}

// ---------------------------------------------------------------------------
extern "C" void kernel_launch(void* const* d_in, const int* in_sizes, int n_in,
                              void* d_out, int out_size, void* d_ws, size_t ws_size,
                              hipStream_t stream)
{
    const float* x           = (const float*)d_in[0];
    const float* car_w       = (const float*)d_in[1];
    const float* cdr_w       = (const float*)d_in[2];
    const float* cons1_w     = (const float*)d_in[3];
    const float* cons2_w     = (const float*)d_in[4];
    const float* root_filler = (const float*)d_in[5];
    const float* Dl          = (const float*)d_in[6];
    const float* Dr          = (const float*)d_in[7];
    const float* El          = (const float*)d_in[8];
    const float* Er          = (const float*)d_in[9];
    const float* root_role   = (const float*)d_in[10];
    float* out = (float*)d_out;

    bf16* args = (bf16*)d_ws;                 // 16,777,216 bf16 = 33.5 MB
    bf16* dpad = args + 16777216;             //  4,194,304 bf16 =  8.4 MB

    k_args <<<dim3(4096),      dim3(256), 0, stream>>>(x, car_w, cdr_w, cons1_w, cons2_w, args);
    k_convd<<<dim3(16384),     dim3(256), 0, stream>>>(Dl, Dr, El, Er, dpad);
    k_gemm <<<dim3(32, 8, 3),  dim3(256), 0, stream>>>(args, dpad, root_filler, root_role, out);
    k_stats<<<dim3(1),         dim3(256), 0, stream>>>(car_w, cdr_w, cons1_w, cons2_w, out);
}

// Round 2
// 135.468 us; speedup vs baseline: 1.0707x; 1.0707x over previous
//
#include <hip/hip_runtime.h>
#include <hip/hip_bf16.h>
#include <stdint.h>

#define Rdim 1023
#define BFR  4190208           // 64*64*1023

typedef __bf16 bf16;
typedef __bf16 bf16x8 __attribute__((ext_vector_type(8)));
typedef __bf16 bf16x4 __attribute__((ext_vector_type(4)));
typedef float  f32x4  __attribute__((ext_vector_type(4)));
typedef float  f32x4u __attribute__((ext_vector_type(4), aligned(4)));  // 4B-aligned vec load

// async global->LDS 16B copy (LDS base must be wave-uniform; HW adds lane*16)
__device__ __forceinline__ void async16(const void* g, void* l) {
    __builtin_amdgcn_global_load_lds(
        (const __attribute__((address_space(1))) void*)g,
        (__attribute__((address_space(3))) void*)l, 16, 0, 0);
}

// ---------------------------------------------------------------------------
// Fused prep kernel.
//  blocks [0,4096):    4-way weighted reduce over l -> bf16 args, CHUNK-SWIZZLED
//  blocks [4096,6144): role matrices fp32->bf16, padded+CHUNK-SWIZZLED
//  block  6144:        entropies + maxes
//
// Swizzle convention (shared with k_gemm): a row of K bf16 is 16B chunks
// c = k/8; data for logical chunk c of row m is stored at chunk (c ^ (m&7)).
// XOR touches only low 3 bits -> every 128B K-step window keeps its 8 chunks,
// so GEMM staging is a LINEAR copy and ds_read applies the same XOR.
// ---------------------------------------------------------------------------
__global__ __launch_bounds__(256) void k_prep(
    const float* __restrict__ x,
    const float* __restrict__ w0, const float* __restrict__ w1,
    const float* __restrict__ w2, const float* __restrict__ w3,
    const float* __restrict__ Dl, const float* __restrict__ Dr,
    const float* __restrict__ El, const float* __restrict__ Er,
    bf16* __restrict__ args, bf16* __restrict__ dpad,
    float* __restrict__ out)
{
    const int blk = blockIdx.x;
    const int t   = threadIdx.x;

    if (blk < 4096) {
        // ---- args: m = blk = b*64+f, thread t owns r = t*4 .. t*4+3 ----
        const int b = blk >> 6;
        float wr0[16], wr1[16], wr2[16], wr3[16];
#pragma unroll
        for (int l = 0; l < 16; ++l) {
            wr0[l] = w0[b*16 + l]; wr1[l] = w1[b*16 + l];
            wr2[l] = w2[b*16 + l]; wr3[l] = w3[b*16 + l];
        }
        const float* xb = x + ((size_t)(b*16)*64 + (blk & 63)) * (size_t)Rdim;
        float a0[4] = {}, a1[4] = {}, a2[4] = {}, a3[4] = {};
        if (t < 255) {
#pragma unroll
            for (int l = 0; l < 16; ++l) {
                f32x4u v = *(const f32x4u*)(xb + (size_t)l*(64*(size_t)Rdim) + t*4);
#pragma unroll
                for (int j = 0; j < 4; ++j) {
                    a0[j] += wr0[l]*v[j]; a1[j] += wr1[l]*v[j];
                    a2[j] += wr2[l]*v[j]; a3[j] += wr3[l]*v[j];
                }
            }
        } else {
            // tail: r = 1020..1022 valid, r=1023 is pad (stays 0); avoids 4B OOB
#pragma unroll
            for (int l = 0; l < 16; ++l) {
                const float* p = xb + (size_t)l*(64*(size_t)Rdim) + 1020;
#pragma unroll
                for (int j = 0; j < 3; ++j) {
                    float v = p[j];
                    a0[j] += wr0[l]*v; a1[j] += wr1[l]*v;
                    a2[j] += wr2[l]*v; a3[j] += wr3[l]*v;
                }
            }
        }
        const int c   = t >> 1;                       // 16B chunk = r/8
        const int S   = blk & 7;
        const int off = ((c ^ S) << 3) + ((t & 1) << 2);
        bf16x4 s0, s1, s2, s3;
#pragma unroll
        for (int j = 0; j < 4; ++j) {
            s0[j] = (bf16)a0[j]; s1[j] = (bf16)a1[j];
            s2[j] = (bf16)a2[j]; s3[j] = (bf16)a3[j];
        }
        *(bf16x4*)(args +            (size_t)blk*1024 + off) = s0;   // car
        *(bf16x4*)(args + 4194304 +  (size_t)blk*1024 + off) = s1;   // cdr
        bf16* c12 = args + 8388608 + (size_t)blk*2048;
        *(bf16x4*)(c12 + off)        = s2;                           // c1 (chunks 0..127)
        *(bf16x4*)(c12 + 1024 + off) = s3;                           // c2 (chunks 128..255)
    } else if (blk < 6144) {
        // ---- dpad: one 16B chunk per thread ----
        const int id = (blk - 4096)*256 + t;          // 0 .. 524287
        const float* src; int n, c, K; size_t base;
        if (id < 262144) {
            const int m2  = id >> 17;                 // 0=Dl 1=Dr
            src = m2 ? Dr : Dl;
            const int rem = id & 131071;
            n = rem >> 7; c = rem & 127; K = 1024;
            base = m2 ? 1048576u : 0u;
        } else {
            const int rem = id - 262144;
            n = rem >> 8; c = rem & 255; K = 2048;    // c<128: E_l, else E_r
            base = 2097152u;
            src = (c < 128) ? El : Er;
        }
        const int cl = c & 127;
        float v[8] = {};
        if (n < Rdim) {
            const float* sp = src + (size_t)n*Rdim + cl*8;
            if (cl < 127) {
                f32x4u u0 = *(const f32x4u*)sp;
                f32x4u u1 = *(const f32x4u*)(sp + 4);
#pragma unroll
                for (int j = 0; j < 4; ++j) { v[j] = u0[j]; v[4+j] = u1[j]; }
            } else {
                f32x4u u0 = *(const f32x4u*)sp;
#pragma unroll
                for (int j = 0; j < 4; ++j) v[j] = u0[j];
                v[4] = sp[4]; v[5] = sp[5]; v[6] = sp[6];   // col 1023 = pad
            }
        }
        const int swc = c ^ (n & 7);
        bf16x8 s;
#pragma unroll
        for (int j = 0; j < 8; ++j) s[j] = (bf16)v[j];
        *(bf16x8*)(dpad + base + (size_t)n*K + swc*8) = s;
    } else {
        // ---- stats ----
        const int k = t >> 6, b2 = t & 63;
        const float* w = (k==0) ? w0 : (k==1) ? w1 : (k==2) ? w2 : w3;
        float s = 0.f, mx = -1e30f;
#pragma unroll
        for (int l = 0; l < 16; ++l) {
            float p = w[b2*16 + l];
            s += p * logf(p + 1e-12f);
            mx = fmaxf(mx, p);
        }
        out[3*(size_t)BFR +       k*64 + b2] = -s / logf(16.f);
        out[3*(size_t)BFR + 256 + k*64 + b2] = mx;
    }
}

// ---------------------------------------------------------------------------
// MFMA GEMM, BK=64, swizzled LDS (sources pre-swizzled -> staging is linear).
// C[m,n] = sum_k A[m,k]*Bm[n,k]; 128x128 tile, 4 waves 2x2, 16x16x32 bf16.
// grid = (32, 8, 3); z = job {car, cdr, cons}
// ---------------------------------------------------------------------------
__global__ __launch_bounds__(256) void k_gemm(
    const bf16* __restrict__ args, const bf16* __restrict__ dpad,
    const float* __restrict__ root_filler, const float* __restrict__ root_role,
    float* __restrict__ out)
{
    const int job = blockIdx.z;
    const int tm  = blockIdx.x;       // 0..31
    const int tn  = blockIdx.y;       // 0..7
    const int K   = (job == 2) ? 2048 : 1024;

    const bf16* A  = args + ((job == 0) ? 0u : (job == 1) ? 4194304u : 8388608u);
    const bf16* Bm = dpad + ((job == 0) ? 0u : (job == 1) ? 1048576u : 2097152u);
    float* outp = out + (size_t)job * BFR;

    __shared__ bf16 As[128 * 64];     // 16 KiB
    __shared__ bf16 Bs[128 * 64];     // 16 KiB

    const int t    = threadIdx.x;
    const int wave = t >> 6, lane = t & 63;
    const int wr   = wave >> 1, wc = wave & 1;
    const int lr   = lane & 15, lk = lane >> 4;

    f32x4 acc[4][4] = {};

    // staging: pass p covers rows p*32 + t/8, chunk t%8 (linear copy of
    // pre-swizzled global data)
    const size_t rowB  = (size_t)K * 2;      // bytes per row
    const size_t passS = 32 * rowB;
    const int   srow  = t >> 3;
    const int   scolB = (t & 7) * 16;
    const char* Ag = (const char*)A  + (size_t)(tm*128 + srow)*rowB + scolB;
    const char* Bg = (const char*)Bm + (size_t)(tn*128 + srow)*rowB + scolB;
    char* AsW = (char*)As + wave * 1024;     // wave-uniform LDS bases
    char* BsW = (char*)Bs + wave * 1024;

    // swizzled chunk indices: c' = (h*4+lk) ^ (lr&7); row bits 3+ drop out
    const int lm  = lr & 7;
    const int c0  = lk ^ lm;          // h=0 (k-offset  0..31)
    const int c1s = (4 + lk) ^ lm;    // h=1 (k-offset 32..63)

    for (int k0 = 0; k0 < K; k0 += 64) {
        const size_t kb = (size_t)k0 * 2;
#pragma unroll
        for (int p = 0; p < 4; ++p) async16(Ag + kb + p*passS, AsW + p*4096);
#pragma unroll
        for (int p = 0; p < 4; ++p) async16(Bg + kb + p*passS, BsW + p*4096);
        __syncthreads();

        bf16x8 af0[4], af1[4], bf0[4], bf1[4];
#pragma unroll
        for (int i = 0; i < 4; ++i) {
            const int ra = (wr*64 + i*16 + lr) * 64;
            af0[i] = *(const bf16x8*)(As + ra + c0*8);
            af1[i] = *(const bf16x8*)(As + ra + c1s*8);
        }
#pragma unroll
        for (int j = 0; j < 4; ++j) {
            const int rb = (wc*64 + j*16 + lr) * 64;
            bf0[j] = *(const bf16x8*)(Bs + rb + c0*8);
            bf1[j] = *(const bf16x8*)(Bs + rb + c1s*8);
        }
#pragma unroll
        for (int i = 0; i < 4; ++i)
#pragma unroll
            for (int j = 0; j < 4; ++j)
                acc[i][j] = __builtin_amdgcn_mfma_f32_16x16x32_bf16(af0[i], bf0[j], acc[i][j], 0, 0, 0);
#pragma unroll
        for (int i = 0; i < 4; ++i)
#pragma unroll
            for (int j = 0; j < 4; ++j)
                acc[i][j] = __builtin_amdgcn_mfma_f32_16x16x32_bf16(af1[i], bf1[j], acc[i][j], 0, 0, 0);
        __syncthreads();
    }

    // epilogue: C/D layout col = lane&15, row = (lane>>4)*4 + q (verified r0)
#pragma unroll
    for (int i = 0; i < 4; ++i) {
        int gm = tm*128 + wr*64 + i*16 + lk*4;
#pragma unroll
        for (int j = 0; j < 4; ++j) {
            int gn = tn*128 + wc*64 + j*16 + lr;
            if (gn < Rdim) {
                float rr = (job == 2) ? root_role[gn] : 0.f;
#pragma unroll
                for (int q = 0; q < 4; ++q) {
                    float v = acc[i][j][q];
                    if (job == 2) v += root_filler[gm + q] * rr;
                    outp[(size_t)(gm + q) * Rdim + gn] = v;
                }
            }
        }
    }
}

// ---------------------------------------------------------------------------
extern "C" void kernel_launch(void* const* d_in, const int* in_sizes, int n_in,
                              void* d_out, int out_size, void* d_ws, size_t ws_size,
                              hipStream_t stream)
{
    const float* x           = (const float*)d_in[0];
    const float* car_w       = (const float*)d_in[1];
    const float* cdr_w       = (const float*)d_in[2];
    const float* cons1_w     = (const float*)d_in[3];
    const float* cons2_w     = (const float*)d_in[4];
    const float* root_filler = (const float*)d_in[5];
    const float* Dl          = (const float*)d_in[6];
    const float* Dr          = (const float*)d_in[7];
    const float* El          = (const float*)d_in[8];
    const float* Er          = (const float*)d_in[9];
    const float* root_role   = (const float*)d_in[10];
    float* out = (float*)d_out;

    bf16* args = (bf16*)d_ws;                 // 16,777,216 bf16 = 33.5 MB
    bf16* dpad = args + 16777216;             //  4,194,304 bf16 =  8.4 MB

    k_prep<<<dim3(6145),     dim3(256), 0, stream>>>(
        x, car_w, cdr_w, cons1_w, cons2_w, Dl, Dr, El, Er, args, dpad, out);
    k_gemm<<<dim3(32, 8, 3), dim3(256), 0, stream>>>(
        args, dpad, root_filler, root_role, out);
}

// Round 3
// 125.852 us; speedup vs baseline: 1.1525x; 1.0764x over previous
//
#include <hip/hip_runtime.h>
#include <hip/hip_bf16.h>
#include <stdint.h>

#define Rdim 1023
#define BFR  4190208           // 64*64*1023

typedef __bf16 bf16;
typedef __bf16 bf16x8 __attribute__((ext_vector_type(8)));
typedef __bf16 bf16x4 __attribute__((ext_vector_type(4)));
typedef float  f32x4  __attribute__((ext_vector_type(4)));
typedef float  f32x4u __attribute__((ext_vector_type(4), aligned(4)));

__device__ __forceinline__ void async16(const void* g, void* l) {
    __builtin_amdgcn_global_load_lds(
        (const __attribute__((address_space(1))) void*)g,
        (__attribute__((address_space(3))) void*)l, 16, 0, 0);
}

// ---------------------------------------------------------------------------
// Fused prep kernel (unchanged from round 2 — works, near HBM floor).
// Swizzle: 16B chunk c of row m stored at chunk (c ^ (m&7)) within its
// 128B (8-chunk) window -> GEMM staging is a LINEAR copy, ds_read XORs.
// ---------------------------------------------------------------------------
__global__ __launch_bounds__(256) void k_prep(
    const float* __restrict__ x,
    const float* __restrict__ w0, const float* __restrict__ w1,
    const float* __restrict__ w2, const float* __restrict__ w3,
    const float* __restrict__ Dl, const float* __restrict__ Dr,
    const float* __restrict__ El, const float* __restrict__ Er,
    bf16* __restrict__ args, bf16* __restrict__ dpad,
    float* __restrict__ out)
{
    const int blk = blockIdx.x;
    const int t   = threadIdx.x;

    if (blk < 4096) {
        const int b = blk >> 6;
        float wr0[16], wr1[16], wr2[16], wr3[16];
#pragma unroll
        for (int l = 0; l < 16; ++l) {
            wr0[l] = w0[b*16 + l]; wr1[l] = w1[b*16 + l];
            wr2[l] = w2[b*16 + l]; wr3[l] = w3[b*16 + l];
        }
        const float* xb = x + ((size_t)(b*16)*64 + (blk & 63)) * (size_t)Rdim;
        float a0[4] = {}, a1[4] = {}, a2[4] = {}, a3[4] = {};
        if (t < 255) {
#pragma unroll
            for (int l = 0; l < 16; ++l) {
                f32x4u v = *(const f32x4u*)(xb + (size_t)l*(64*(size_t)Rdim) + t*4);
#pragma unroll
                for (int j = 0; j < 4; ++j) {
                    a0[j] += wr0[l]*v[j]; a1[j] += wr1[l]*v[j];
                    a2[j] += wr2[l]*v[j]; a3[j] += wr3[l]*v[j];
                }
            }
        } else {
#pragma unroll
            for (int l = 0; l < 16; ++l) {
                const float* p = xb + (size_t)l*(64*(size_t)Rdim) + 1020;
#pragma unroll
                for (int j = 0; j < 3; ++j) {
                    float v = p[j];
                    a0[j] += wr0[l]*v; a1[j] += wr1[l]*v;
                    a2[j] += wr2[l]*v; a3[j] += wr3[l]*v;
                }
            }
        }
        const int c   = t >> 1;
        const int S   = blk & 7;
        const int off = ((c ^ S) << 3) + ((t & 1) << 2);
        bf16x4 s0, s1, s2, s3;
#pragma unroll
        for (int j = 0; j < 4; ++j) {
            s0[j] = (bf16)a0[j]; s1[j] = (bf16)a1[j];
            s2[j] = (bf16)a2[j]; s3[j] = (bf16)a3[j];
        }
        *(bf16x4*)(args +            (size_t)blk*1024 + off) = s0;
        *(bf16x4*)(args + 4194304 +  (size_t)blk*1024 + off) = s1;
        bf16* c12 = args + 8388608 + (size_t)blk*2048;
        *(bf16x4*)(c12 + off)        = s2;
        *(bf16x4*)(c12 + 1024 + off) = s3;
    } else if (blk < 6144) {
        const int id = (blk - 4096)*256 + t;
        const float* src; int n, c, K; size_t base;
        if (id < 262144) {
            const int m2  = id >> 17;
            src = m2 ? Dr : Dl;
            const int rem = id & 131071;
            n = rem >> 7; c = rem & 127; K = 1024;
            base = m2 ? 1048576u : 0u;
        } else {
            const int rem = id - 262144;
            n = rem >> 8; c = rem & 255; K = 2048;
            base = 2097152u;
            src = (c < 128) ? El : Er;
        }
        const int cl = c & 127;
        float v[8] = {};
        if (n < Rdim) {
            const float* sp = src + (size_t)n*Rdim + cl*8;
            if (cl < 127) {
                f32x4u u0 = *(const f32x4u*)sp;
                f32x4u u1 = *(const f32x4u*)(sp + 4);
#pragma unroll
                for (int j = 0; j < 4; ++j) { v[j] = u0[j]; v[4+j] = u1[j]; }
            } else {
                f32x4u u0 = *(const f32x4u*)sp;
#pragma unroll
                for (int j = 0; j < 4; ++j) v[j] = u0[j];
                v[4] = sp[4]; v[5] = sp[5]; v[6] = sp[6];
            }
        }
        const int swc = c ^ (n & 7);
        bf16x8 s;
#pragma unroll
        for (int j = 0; j < 8; ++j) s[j] = (bf16)v[j];
        *(bf16x8*)(dpad + base + (size_t)n*K + swc*8) = s;
    } else {
        const int k = t >> 6, b2 = t & 63;
        const float* w = (k==0) ? w0 : (k==1) ? w1 : (k==2) ? w2 : w3;
        float s = 0.f, mx = -1e30f;
#pragma unroll
        for (int l = 0; l < 16; ++l) {
            float p = w[b2*16 + l];
            s += p * logf(p + 1e-12f);
            mx = fmaxf(mx, p);
        }
        out[3*(size_t)BFR +       k*64 + b2] = -s / logf(16.f);
        out[3*(size_t)BFR + 256 + k*64 + b2] = mx;
    }
}

// ---------------------------------------------------------------------------
// 256x256 8-phase MFMA GEMM (T1+T2+T3+T4+T5). 8 waves (2M x 4N), BK=64,
// 2 K-tiles/iter, LDS 128 KiB (A/B x 2 dbuf x 2 half x [128][64]bf16).
// grid = 256 blocks: 4 jobs {car, cdr, cons1, cons2} x 16 mt x 4 nt, K=1024.
// Stage slots/iter: P1 A'h0 P2 A'h1 | P3 B''h0 P4 B''h1 | P5 A''h0 P6 A''h1 |
// P7 B'''h0 P8 B'''h1, vmcnt(4) at P4/P8 (2 half-tiles in flight).
// ---------------------------------------------------------------------------
#define BAR()  do { __builtin_amdgcn_s_barrier(); __builtin_amdgcn_sched_barrier(0); } while(0)

#define LDA(DST, buf, ih) do {                                                \
    const char* _b = lds + (buf)*32768 + wm*16384;                            \
    _Pragma("unroll") for (int i2 = 0; i2 < 4; ++i2)                          \
    _Pragma("unroll") for (int ks = 0; ks < 2; ++ks)                          \
        DST[i2*2+ks] = *(const bf16x8*)(_b + ((ih)*64 + i2*16 + lr)*128       \
                                           + (((ks*4+lk)^lm)<<4));            \
} while(0)

#define LDB(DST, buf, jh) do {                                                \
    const char* _b = lds + 65536 + (buf)*32768 + (wn>>1)*16384 + (wn&1)*8192; \
    _Pragma("unroll") for (int j2 = 0; j2 < 2; ++j2)                          \
    _Pragma("unroll") for (int ks = 0; ks < 2; ++ks)                          \
        DST[j2*2+ks] = *(const bf16x8*)(_b + ((jh)*32 + j2*16 + lr)*128       \
                                           + (((ks*4+lk)^lm)<<4));            \
} while(0)

#define MMQ(AF, BF, ih, jh) do {                                              \
    __builtin_amdgcn_s_setprio(1);                                            \
    _Pragma("unroll") for (int i2 = 0; i2 < 4; ++i2)                          \
    _Pragma("unroll") for (int j2 = 0; j2 < 2; ++j2)                          \
    _Pragma("unroll") for (int ks = 0; ks < 2; ++ks)                          \
        acc[(ih)*4+i2][(jh)*2+j2] = __builtin_amdgcn_mfma_f32_16x16x32_bf16(  \
            AF[i2*2+ks], BF[j2*2+ks], acc[(ih)*4+i2][(jh)*2+j2], 0, 0, 0);    \
    __builtin_amdgcn_s_setprio(0);                                            \
} while(0)

#define STAGE_A(buf, half, kt) do {                                           \
    const char* _g = AgT + (size_t)((half)*128)*AstB + (size_t)(kt)*128;      \
    char* _l = lds + (buf)*32768 + (half)*16384 + wave*1024;                  \
    async16(_g, _l); async16(_g + 64*(size_t)AstB, _l + 8192);                \
} while(0)

#define STAGE_B(buf, half, kt) do {                                           \
    const char* _g = BgT + (size_t)((half)*128)*AstB + (size_t)(kt)*128;      \
    char* _l = lds + 65536 + (buf)*32768 + (half)*16384 + wave*1024;          \
    async16(_g, _l); async16(_g + 64*(size_t)AstB, _l + 8192);                \
} while(0)

__global__ __launch_bounds__(512, 2) void k_gemm8(
    const bf16* __restrict__ args, const bf16* __restrict__ dpad,
    const float* __restrict__ root_filler, const float* __restrict__ root_role,
    float* __restrict__ out, float* __restrict__ P)
{
    __shared__ bf16 ldsbuf[65536];            // 128 KiB
    char* lds = (char*)ldsbuf;

    const int bid = blockIdx.x;
    const int swz = (bid & 7)*32 + (bid >> 3);     // XCD-aware, bijective (256%8==0)
    const int job = swz >> 6;
    const int mt  = (swz >> 2) & 15;
    const int nt  = swz & 3;

    const bf16* Ab = (job==0) ? args : (job==1) ? args+4194304
                   : (job==2) ? args+8388608 : args+8389632;
    const bf16* Bb = (job==0) ? dpad : (job==1) ? dpad+1048576
                   : (job==2) ? dpad+2097152 : dpad+2098176;
    const int AstB = (job < 2) ? 2048 : 4096;      // row stride in BYTES (A and B)

    const int tid  = threadIdx.x;
    const int wave = tid >> 6, lane = tid & 63;
    const int wm   = wave >> 2, wn = wave & 3;     // 2M x 4N
    const int lr   = lane & 15, lk = lane >> 4, lm = lane & 7;

    const char* AgT = (const char*)Ab + (size_t)(mt*256 + (tid>>3))*AstB + (tid&7)*16;
    const char* BgT = (const char*)Bb + (size_t)(nt*256 + (tid>>3))*AstB + (tid&7)*16;

    f32x4 acc[8][4] = {};
    bf16x8 afA[8], afB[8], bfA[4], bfB[4];

    // prologue: kt0 A+B -> buf0, kt1 B -> buf1; wait all but last 4 loads
    STAGE_B(0, 0, 0); STAGE_B(0, 1, 0);
    STAGE_A(0, 0, 0); STAGE_A(0, 1, 0);
    STAGE_B(1, 0, 1); STAGE_B(1, 1, 1);
    asm volatile("s_waitcnt vmcnt(4)" ::: "memory");
    BAR();

    for (int t = 0; t < 8; ++t) {
        const int k1 = 2*t+1, k2 = 2*t+2, k3 = 2*t+3;
        const bool more = (t < 7);
        // P1
        LDA(afA, 0, 0); LDB(bfA, 0, 0);
        STAGE_A(1, 0, k1);
        BAR();
        MMQ(afA, bfA, 0, 0);
        BAR();
        // P2
        LDB(bfB, 0, 1);
        STAGE_A(1, 1, k1);
        BAR();
        MMQ(afA, bfB, 0, 1);
        BAR();
        // P3
        LDA(afB, 0, 1);
        if (more) STAGE_B(0, 0, k2);
        BAR();
        MMQ(afB, bfA, 1, 0);
        BAR();
        // P4
        if (more) STAGE_B(0, 1, k2);
        BAR();
        MMQ(afB, bfB, 1, 1);
        if (more) { asm volatile("s_waitcnt vmcnt(4)" ::: "memory"); }
        else      { asm volatile("s_waitcnt vmcnt(0)" ::: "memory"); }
        BAR();
        // P5
        LDA(afA, 1, 0); LDB(bfA, 1, 0);
        if (more) STAGE_A(0, 0, k2);
        BAR();
        MMQ(afA, bfA, 0, 0);
        BAR();
        // P6
        LDB(bfB, 1, 1);
        if (more) STAGE_A(0, 1, k2);
        BAR();
        MMQ(afA, bfB, 0, 1);
        BAR();
        // P7
        LDA(afB, 1, 1);
        if (more) STAGE_B(1, 0, k3);
        BAR();
        MMQ(afB, bfA, 1, 0);
        BAR();
        // P8
        if (more) STAGE_B(1, 1, k3);
        BAR();
        MMQ(afB, bfB, 1, 1);
        if (more) { asm volatile("s_waitcnt vmcnt(4)" ::: "memory"); }
        BAR();
    }

    float* outp = (job < 3) ? (out + (size_t)job*BFR) : P;

#pragma unroll
    for (int i = 0; i < 8; ++i) {
        const int gm = mt*256 + wm*128 + i*16 + lk*4;
#pragma unroll
        for (int j = 0; j < 4; ++j) {
            const int gn = nt*256 + wn*64 + j*16 + lr;
            if (gn < Rdim) {
                const float rr = (job == 2) ? root_role[gn] : 0.f;
#pragma unroll
                for (int q = 0; q < 4; ++q) {
                    float v = acc[i][j][q];
                    if (job == 2) v += root_filler[gm + q] * rr;
                    outp[(size_t)(gm + q)*Rdim + gn] = v;
                }
            }
        }
    }
}

// ---------------------------------------------------------------------------
// merge: out_cons += P   (4,190,208 floats = 1,047,552 float4)
// ---------------------------------------------------------------------------
__global__ __launch_bounds__(256) void k_merge(
    const float* __restrict__ P, float* __restrict__ out)
{
    const int i = blockIdx.x*256 + threadIdx.x;
    float* o = out + 2*(size_t)BFR;
#pragma unroll
    for (int r = 0; r < 4; ++r) {
        const int v = i + r*262144;
        f32x4 a = *(const f32x4*)(o + (size_t)v*4);
        f32x4 b = *(const f32x4*)(P + (size_t)v*4);
        a = a + b;
        *(f32x4*)(o + (size_t)v*4) = a;
    }
}

// ---------------------------------------------------------------------------
extern "C" void kernel_launch(void* const* d_in, const int* in_sizes, int n_in,
                              void* d_out, int out_size, void* d_ws, size_t ws_size,
                              hipStream_t stream)
{
    const float* x           = (const float*)d_in[0];
    const float* car_w       = (const float*)d_in[1];
    const float* cdr_w       = (const float*)d_in[2];
    const float* cons1_w     = (const float*)d_in[3];
    const float* cons2_w     = (const float*)d_in[4];
    const float* root_filler = (const float*)d_in[5];
    const float* Dl          = (const float*)d_in[6];
    const float* Dr          = (const float*)d_in[7];
    const float* El          = (const float*)d_in[8];
    const float* Er          = (const float*)d_in[9];
    const float* root_role   = (const float*)d_in[10];
    float* out = (float*)d_out;

    bf16*  args = (bf16*)d_ws;                        // 33.5 MB
    bf16*  dpad = args + 16777216;                    //  8.4 MB
    float* P    = (float*)((char*)d_ws + 41943040);   // 16.8 MB partial (cons2)

    k_prep <<<dim3(6145), dim3(256), 0, stream>>>(
        x, car_w, cdr_w, cons1_w, cons2_w, Dl, Dr, El, Er, args, dpad, out);
    k_gemm8<<<dim3(256),  dim3(512), 0, stream>>>(
        args, dpad, root_filler, root_role, out, P);
    k_merge<<<dim3(1024), dim3(256), 0, stream>>>(P, out);
}

// Round 4
// 111.361 us; speedup vs baseline: 1.3025x; 1.1301x over previous
//
#include <hip/hip_runtime.h>
#include <hip/hip_bf16.h>
#include <stdint.h>

#define Rdim 1023
#define BFR  4190208           // 64*64*1023

typedef __bf16 bf16;
typedef __bf16 bf16x8 __attribute__((ext_vector_type(8)));
typedef __bf16 bf16x4 __attribute__((ext_vector_type(4)));
typedef float  f32x4  __attribute__((ext_vector_type(4)));
typedef float  f32x4u __attribute__((ext_vector_type(4), aligned(4)));

__device__ __forceinline__ void async16(const void* g, void* l) {
    __builtin_amdgcn_global_load_lds(
        (const __attribute__((address_space(1))) void*)g,
        (__attribute__((address_space(3))) void*)l, 16, 0, 0);
}

// ---------------------------------------------------------------------------
// Fused prep kernel (unchanged — proven, near HBM floor).
// Swizzle: 16B chunk c of row m stored at chunk (c ^ (m&7)) within its
// 128B (8-chunk) window -> GEMM staging is a LINEAR copy, ds_read XORs.
// ---------------------------------------------------------------------------
__global__ __launch_bounds__(256) void k_prep(
    const float* __restrict__ x,
    const float* __restrict__ w0, const float* __restrict__ w1,
    const float* __restrict__ w2, const float* __restrict__ w3,
    const float* __restrict__ Dl, const float* __restrict__ Dr,
    const float* __restrict__ El, const float* __restrict__ Er,
    bf16* __restrict__ args, bf16* __restrict__ dpad,
    float* __restrict__ out)
{
    const int blk = blockIdx.x;
    const int t   = threadIdx.x;

    if (blk < 4096) {
        const int b = blk >> 6;
        float wr0[16], wr1[16], wr2[16], wr3[16];
#pragma unroll
        for (int l = 0; l < 16; ++l) {
            wr0[l] = w0[b*16 + l]; wr1[l] = w1[b*16 + l];
            wr2[l] = w2[b*16 + l]; wr3[l] = w3[b*16 + l];
        }
        const float* xb = x + ((size_t)(b*16)*64 + (blk & 63)) * (size_t)Rdim;
        float a0[4] = {}, a1[4] = {}, a2[4] = {}, a3[4] = {};
        if (t < 255) {
#pragma unroll
            for (int l = 0; l < 16; ++l) {
                f32x4u v = *(const f32x4u*)(xb + (size_t)l*(64*(size_t)Rdim) + t*4);
#pragma unroll
                for (int j = 0; j < 4; ++j) {
                    a0[j] += wr0[l]*v[j]; a1[j] += wr1[l]*v[j];
                    a2[j] += wr2[l]*v[j]; a3[j] += wr3[l]*v[j];
                }
            }
        } else {
#pragma unroll
            for (int l = 0; l < 16; ++l) {
                const float* p = xb + (size_t)l*(64*(size_t)Rdim) + 1020;
#pragma unroll
                for (int j = 0; j < 3; ++j) {
                    float v = p[j];
                    a0[j] += wr0[l]*v; a1[j] += wr1[l]*v;
                    a2[j] += wr2[l]*v; a3[j] += wr3[l]*v;
                }
            }
        }
        const int c   = t >> 1;
        const int S   = blk & 7;
        const int off = ((c ^ S) << 3) + ((t & 1) << 2);
        bf16x4 s0, s1, s2, s3;
#pragma unroll
        for (int j = 0; j < 4; ++j) {
            s0[j] = (bf16)a0[j]; s1[j] = (bf16)a1[j];
            s2[j] = (bf16)a2[j]; s3[j] = (bf16)a3[j];
        }
        *(bf16x4*)(args +            (size_t)blk*1024 + off) = s0;
        *(bf16x4*)(args + 4194304 +  (size_t)blk*1024 + off) = s1;
        bf16* c12 = args + 8388608 + (size_t)blk*2048;
        *(bf16x4*)(c12 + off)        = s2;
        *(bf16x4*)(c12 + 1024 + off) = s3;
    } else if (blk < 6144) {
        const int id = (blk - 4096)*256 + t;
        const float* src; int n, c, K; size_t base;
        if (id < 262144) {
            const int m2  = id >> 17;
            src = m2 ? Dr : Dl;
            const int rem = id & 131071;
            n = rem >> 7; c = rem & 127; K = 1024;
            base = m2 ? 1048576u : 0u;
        } else {
            const int rem = id - 262144;
            n = rem >> 8; c = rem & 255; K = 2048;
            base = 2097152u;
            src = (c < 128) ? El : Er;
        }
        const int cl = c & 127;
        float v[8] = {};
        if (n < Rdim) {
            const float* sp = src + (size_t)n*Rdim + cl*8;
            if (cl < 127) {
                f32x4u u0 = *(const f32x4u*)sp;
                f32x4u u1 = *(const f32x4u*)(sp + 4);
#pragma unroll
                for (int j = 0; j < 4; ++j) { v[j] = u0[j]; v[4+j] = u1[j]; }
            } else {
                f32x4u u0 = *(const f32x4u*)sp;
#pragma unroll
                for (int j = 0; j < 4; ++j) v[j] = u0[j];
                v[4] = sp[4]; v[5] = sp[5]; v[6] = sp[6];
            }
        }
        const int swc = c ^ (n & 7);
        bf16x8 s;
#pragma unroll
        for (int j = 0; j < 8; ++j) s[j] = (bf16)v[j];
        *(bf16x8*)(dpad + base + (size_t)n*K + swc*8) = s;
    } else {
        const int k = t >> 6, b2 = t & 63;
        const float* w = (k==0) ? w0 : (k==1) ? w1 : (k==2) ? w2 : w3;
        float s = 0.f, mx = -1e30f;
#pragma unroll
        for (int l = 0; l < 16; ++l) {
            float p = w[b2*16 + l];
            s += p * logf(p + 1e-12f);
            mx = fmaxf(mx, p);
        }
        out[3*(size_t)BFR +       k*64 + b2] = -s / logf(16.f);
        out[3*(size_t)BFR + 256 + k*64 + b2] = mx;
    }
}

// ---------------------------------------------------------------------------
// 128x256 MFMA GEMM, uniform tiles, triple-buffered LDS, 2 phases/K-tile.
// 8 waves (4M x 2N): wave = 32 rows x 128 cols = acc[2][8].
// LDS: A bufs 3 x 16KB @0, B bufs 3 x 32KB @49152 -> 144 KiB, 1 block/CU.
// Stage kt+2 during kt (A=2 + B=4 async16 units, 3 per phase), vmcnt(6)/K-tile.
// grid = 384: per XCD 16 cons (K=2048, 1-unit, FIRST) + 16 car + 16 cdr
// (K=1024, 0.5-unit) -> fill-in packing, no merge kernel needed.
// ---------------------------------------------------------------------------
#define BAR()  do { __builtin_amdgcn_s_barrier(); __builtin_amdgcn_sched_barrier(0); } while(0)

#define LDA(CA) do {                                                          \
    _Pragma("unroll") for (int i2 = 0; i2 < 2; ++i2)                          \
    _Pragma("unroll") for (int ks = 0; ks < 2; ++ks)                          \
        af[i2*2+ks] = *(const bf16x8*)((CA) + (wm*32 + i2*16 + lr)*128        \
                                            + (((ks*4+lk)^lm)<<4));           \
} while(0)

#define LDB(CB, JH) do {                                                      \
    _Pragma("unroll") for (int j2 = 0; j2 < 4; ++j2)                          \
    _Pragma("unroll") for (int ks = 0; ks < 2; ++ks)                          \
        bfr[j2*2+ks] = *(const bf16x8*)((CB) + (wn*128 + (JH)*64 + j2*16 + lr)*128 \
                                             + (((ks*4+lk)^lm)<<4));          \
} while(0)

#define MMQ(JH) do {                                                          \
    __builtin_amdgcn_s_setprio(1);                                            \
    _Pragma("unroll") for (int i2 = 0; i2 < 2; ++i2)                          \
    _Pragma("unroll") for (int j2 = 0; j2 < 4; ++j2)                          \
    _Pragma("unroll") for (int ks = 0; ks < 2; ++ks)                          \
        acc[i2][(JH)*4+j2] = __builtin_amdgcn_mfma_f32_16x16x32_bf16(         \
            af[i2*2+ks], bfr[j2*2+ks], acc[i2][(JH)*4+j2], 0, 0, 0);          \
    __builtin_amdgcn_s_setprio(0);                                            \
} while(0)

#define STAGE_A2(SA, kt) do {                                                 \
    const char* _g = AgT + (size_t)(kt)*128;                                  \
    char* _l = (SA) + wave*1024;                                              \
    async16(_g, _l); async16(_g + 64*(size_t)AstB, _l + 8192);                \
} while(0)

#define STAGE_B1(SB, kt) do {                                                 \
    async16(BgT + (size_t)(kt)*128, (SB) + wave*1024);                        \
} while(0)

#define STAGE_B3(SB, kt) do {                                                 \
    const char* _g = BgT + (size_t)(kt)*128;                                  \
    char* _l = (SB) + wave*1024;                                              \
    async16(_g +  64*(size_t)AstB, _l + 8192);                                \
    async16(_g + 128*(size_t)AstB, _l + 16384);                               \
    async16(_g + 192*(size_t)AstB, _l + 24576);                               \
} while(0)

__global__ __launch_bounds__(512, 2) void k_gemm3(
    const bf16* __restrict__ args, const bf16* __restrict__ dpad,
    const float* __restrict__ root_filler, const float* __restrict__ root_role,
    float* __restrict__ out)
{
    __shared__ char lds[147456];      // 144 KiB

    const int bid = blockIdx.x;
    const int xcd = bid & 7, idx = bid >> 3;       // idx 0..47
    int job, tile;
    if (idx < 16)      { job = 2; tile = xcd*16 + idx;      }  // cons FIRST (1-unit)
    else if (idx < 32) { job = 0; tile = xcd*16 + idx - 16; }  // car
    else               { job = 1; tile = xcd*16 + idx - 32; }  // cdr
    const int mt = tile >> 2;       // 0..31  (4 consecutive mt per XCD group)
    const int nt = tile & 3;        // 0..3

    const bf16* Ab = (job==0) ? args : (job==1) ? args+4194304 : args+8388608;
    const bf16* Bb = (job==0) ? dpad : (job==1) ? dpad+1048576 : dpad+2097152;
    const int AstB = (job < 2) ? 2048 : 4096;      // row stride BYTES (A and B)
    const int nkt  = (job < 2) ? 16 : 32;          // K/64

    const int tid  = threadIdx.x;
    const int wave = tid >> 6, lane = tid & 63;
    const int wm   = wave >> 1, wn = wave & 1;     // 4M x 2N
    const int lr   = lane & 15, lk = lane >> 4, lm = lane & 7;

    const char* AgT = (const char*)Ab + (size_t)(mt*128 + (tid>>3))*AstB + (tid&7)*16;
    const char* BgT = (const char*)Bb + (size_t)(nt*256 + (tid>>3))*AstB + (tid&7)*16;

    f32x4 acc[2][8] = {};
    bf16x8 af[4], bfr[8];

    // prologue: kt0 -> buf0, kt1 -> buf1 (6 units each); wait kt0 landed
    STAGE_A2(lds,         0); STAGE_B1(lds + 49152, 0); STAGE_B3(lds + 49152, 0);
    STAGE_A2(lds + 16384, 1); STAGE_B1(lds + 81920, 1); STAGE_B3(lds + 81920, 1);
    asm volatile("s_waitcnt vmcnt(6)" ::: "memory");
    BAR();

    int cb = 0;
    for (int kt = 0; kt < nkt; ++kt) {
        char* cA = lds + cb*16384;
        char* cB = lds + 49152 + cb*32768;
        int sb = cb + 2; if (sb >= 3) sb -= 3;
        char* sA = lds + sb*16384;
        char* sB = lds + 49152 + sb*32768;
        const bool st = (kt + 2 < nkt);
        // P1: read A + B(jh0) of kt; stage 3 units of kt+2
        LDA(cA); LDB(cB, 0);
        if (st) { STAGE_A2(sA, kt+2); STAGE_B1(sB, kt+2); }
        BAR();
        MMQ(0);
        BAR();
        // P2: read B(jh1); stage remaining 3 units; counted vmcnt
        LDB(cB, 1);
        if (st) STAGE_B3(sB, kt+2);
        BAR();
        MMQ(1);
        if (st)                { asm volatile("s_waitcnt vmcnt(6)" ::: "memory"); }
        else if (kt == nkt-2)  { asm volatile("s_waitcnt vmcnt(0)" ::: "memory"); }
        BAR();
        cb = cb + 1; if (cb == 3) cb = 0;
    }

    float* outp = out + (size_t)job * BFR;
#pragma unroll
    for (int i2 = 0; i2 < 2; ++i2) {
        const int gm = mt*128 + wm*32 + i2*16 + lk*4;
#pragma unroll
        for (int jj = 0; jj < 8; ++jj) {
            const int gn = nt*256 + wn*128 + (jj>>2)*64 + (jj&3)*16 + lr;
            if (gn < Rdim) {
                const float rr = (job == 2) ? root_role[gn] : 0.f;
#pragma unroll
                for (int q = 0; q < 4; ++q) {
                    float v = acc[i2][jj][q];
                    if (job == 2) v += root_filler[gm + q] * rr;
                    outp[(size_t)(gm + q)*Rdim + gn] = v;
                }
            }
        }
    }
}

// ---------------------------------------------------------------------------
extern "C" void kernel_launch(void* const* d_in, const int* in_sizes, int n_in,
                              void* d_out, int out_size, void* d_ws, size_t ws_size,
                              hipStream_t stream)
{
    const float* x           = (const float*)d_in[0];
    const float* car_w       = (const float*)d_in[1];
    const float* cdr_w       = (const float*)d_in[2];
    const float* cons1_w     = (const float*)d_in[3];
    const float* cons2_w     = (const float*)d_in[4];
    const float* root_filler = (const float*)d_in[5];
    const float* Dl          = (const float*)d_in[6];
    const float* Dr          = (const float*)d_in[7];
    const float* El          = (const float*)d_in[8];
    const float* Er          = (const float*)d_in[9];
    const float* root_role   = (const float*)d_in[10];
    float* out = (float*)d_out;

    bf16* args = (bf16*)d_ws;                 // 33.5 MB
    bf16* dpad = args + 16777216;             //  8.4 MB

    k_prep <<<dim3(6145), dim3(256), 0, stream>>>(
        x, car_w, cdr_w, cons1_w, cons2_w, Dl, Dr, El, Er, args, dpad, out);
    k_gemm3<<<dim3(384),  dim3(512), 0, stream>>>(
        args, dpad, root_filler, root_role, out);
}